// Round 9
// baseline (242.417 us; speedup 1.0000x reference)
//
#include <hip/hip_runtime.h>
#include <math.h>

typedef unsigned short u16;
typedef __attribute__((ext_vector_type(8))) short short8;
typedef __attribute__((ext_vector_type(4))) float floatx4;

__device__ __forceinline__ float b2f(u16 u) { return __uint_as_float(((unsigned)u) << 16); }
__device__ __forceinline__ u16 f2b(float f) {
  unsigned u = __float_as_uint(f);
  return (u16)((u + 0x7fffu + ((u >> 16) & 1u)) >> 16);
}
__device__ __forceinline__ unsigned pk2(float lo, float hi) {
  return (unsigned)f2b(lo) | ((unsigned)f2b(hi) << 16);
}

// ---------- fused prep: cast x -> bf16 | cast 4 weights | build Wcat ----------
__global__ __launch_bounds__(256) void prep_cast(const float* __restrict__ x, const float* __restrict__ wpr,
                                                 const float* __restrict__ w0, const float* __restrict__ w1,
                                                 const float* __restrict__ w2, const float* __restrict__ qp,
                                                 const float* __restrict__ kp, const float* __restrict__ wv,
                                                 u16* __restrict__ XB, u16* __restrict__ WPRb,
                                                 u16* __restrict__ W0b, u16* __restrict__ W1b,
                                                 u16* __restrict__ W2b, u16* __restrict__ wcat) {
  int bi = blockIdx.x, tid = threadIdx.x;
  if (bi < 2048) {                       // cast_x: 524288 float4s
    int i = bi * 256 + tid;
    float4 v = ((const float4*)x)[i];
    ushort4 o; o.x = f2b(v.x); o.y = f2b(v.y); o.z = f2b(v.z); o.w = f2b(v.w);
    ((ushort4*)XB)[i] = o;
  } else if (bi < 3072) {                // cast 4x 512x512 weights: 262144 float4s
    int i = (bi - 2048) * 256 + tid;
    int sel = i >> 16, j = i & 65535;
    const float* s = sel == 0 ? wpr : sel == 1 ? w0 : sel == 2 ? w1 : w2;
    u16* d = sel == 0 ? WPRb : sel == 1 ? W0b : sel == 2 ? W1b : W2b;
    float4 v = ((const float4*)s)[j];
    ushort4 o; o.x = f2b(v.x); o.y = f2b(v.y); o.z = f2b(v.z); o.w = f2b(v.w);
    ((ushort4*)d)[j] = o;
  } else {                               // build_wcat: 524288 elements
    int i = (bi - 3072) * 256 + tid;
    int d = i & 511, c = i >> 9;
    float v;
    if (c < 512) {
      int hh = c >> 5, o = c & 31;
      const float* src = (hh < 8) ? qp : kp;
      int h = hh & 7;
      v = src[(h * 512 + d) * 32 + o];
    } else {
      v = wv[(c - 512) * 512 + d];
    }
    wcat[i] = f2b(v);
  }
}

// ---------- bf16 MFMA GEMM: BK=64, register prefetch ----------
// C[M x N] = A[M x 512] @ B^T.  EPI: 0 plain, 1 +X. DUAL: also store bf16.
template <int EPI, bool DUAL>
__global__ __launch_bounds__(256) void mgemm(const u16* __restrict__ A, const u16* __restrict__ Bw,
                                             const float* __restrict__ X, float* __restrict__ C,
                                             u16* __restrict__ Cb, int N) {
  __shared__ u16 As[64][72];
  __shared__ u16 Bs[64][72];
  const int tid = threadIdx.x;
  const int bm = blockIdx.y, bn = blockIdx.x;
  const int lane = tid & 63, wave = tid >> 6;
  const int wm = wave >> 1, wn = wave & 1;
  const int quad = lane >> 4, l16 = lane & 15;
  const int sr = tid >> 2;
  const int sk = (tid & 3) << 4;
  floatx4 acc[2][2] = {};
  const u16* Ap = A + (size_t)(bm * 64 + sr) * 512 + sk;
  const u16* Bp = Bw + (size_t)(bn * 64 + sr) * 512 + sk;
  uint4 a0 = *(const uint4*)(Ap);
  uint4 a1 = *(const uint4*)(Ap + 8);
  uint4 b0 = *(const uint4*)(Bp);
  uint4 b1 = *(const uint4*)(Bp + 8);
  for (int k0 = 0; k0 < 512; k0 += 64) {
    __syncthreads();
    *(uint4*)&As[sr][sk] = a0;
    *(uint4*)&As[sr][sk + 8] = a1;
    *(uint4*)&Bs[sr][sk] = b0;
    *(uint4*)&Bs[sr][sk + 8] = b1;
    __syncthreads();
    if (k0 + 64 < 512) {
      a0 = *(const uint4*)(Ap + k0 + 64);
      a1 = *(const uint4*)(Ap + k0 + 72);
      b0 = *(const uint4*)(Bp + k0 + 64);
      b1 = *(const uint4*)(Bp + k0 + 72);
    }
#pragma unroll
    for (int kk = 0; kk < 2; kk++) {
      short8 af0 = *(const short8*)&As[wm * 32 + l16][kk * 32 + quad * 8];
      short8 af1 = *(const short8*)&As[wm * 32 + 16 + l16][kk * 32 + quad * 8];
      short8 bf0 = *(const short8*)&Bs[wn * 32 + l16][kk * 32 + quad * 8];
      short8 bf1 = *(const short8*)&Bs[wn * 32 + 16 + l16][kk * 32 + quad * 8];
      acc[0][0] = __builtin_amdgcn_mfma_f32_16x16x32_bf16(af0, bf0, acc[0][0], 0, 0, 0);
      acc[0][1] = __builtin_amdgcn_mfma_f32_16x16x32_bf16(af0, bf1, acc[0][1], 0, 0, 0);
      acc[1][0] = __builtin_amdgcn_mfma_f32_16x16x32_bf16(af1, bf0, acc[1][0], 0, 0, 0);
      acc[1][1] = __builtin_amdgcn_mfma_f32_16x16x32_bf16(af1, bf1, acc[1][1], 0, 0, 0);
    }
  }
#pragma unroll
  for (int mt = 0; mt < 2; mt++)
#pragma unroll
    for (int r = 0; r < 4; r++) {
      int row = bm * 64 + wm * 32 + mt * 16 + quad * 4 + r;
#pragma unroll
      for (int nt = 0; nt < 2; nt++) {
        int col = bn * 64 + wn * 32 + nt * 16 + l16;
        float v = acc[mt][nt][r];
        if (EPI == 1) v += X[(size_t)row * 512 + col];
        C[(size_t)row * N + col] = v;
        if (DUAL) Cb[(size_t)row * N + col] = f2b(v);
      }
    }
}

// ---------- bf16 MFMA GEMM with fused input LayerNorm + silu/residual epilogue ----------
// C = X + silu( LN(A; g,b) @ Bw^T ).  A,X fp32 (X is the un-normalized residual), C fp32.
__global__ __launch_bounds__(256) void mgemm_ln(const float* __restrict__ A, const u16* __restrict__ Bw,
                                                const float* __restrict__ g, const float* __restrict__ bb,
                                                const float* __restrict__ X, float* __restrict__ C) {
  __shared__ u16 As[64][72];
  __shared__ u16 Bs[64][72];
  __shared__ float meanS[64], rstdS[64];
  __shared__ float gs[512], bs[512];
  const int tid = threadIdx.x;
  const int bm = blockIdx.y, bn = blockIdx.x;
  const int lane = tid & 63, wave = tid >> 6;
  const int wm = wave >> 1, wn = wave & 1;
  const int quad = lane >> 4, l16 = lane & 15;
  const int sr = tid >> 2;
  const int sk = (tid & 3) << 4;  // 16-float chunk
  // preload gamma/beta
  gs[tid] = g[tid]; gs[tid + 256] = g[tid + 256];
  bs[tid] = bb[tid]; bs[tid + 256] = bb[tid + 256];
  // pass 1: row stats (row = tid>>2, 4 threads per row)
  {
    int r = tid >> 2, p = tid & 3;
    const float* Ar = A + (size_t)(bm * 64 + r) * 512 + p * 4;
    float s1 = 0.f, s2 = 0.f;
#pragma unroll 8
    for (int j = 0; j < 32; j++) {
      float4 v = *(const float4*)(Ar + j * 16);
      s1 += v.x + v.y + v.z + v.w;
      s2 = fmaf(v.x, v.x, fmaf(v.y, v.y, fmaf(v.z, v.z, fmaf(v.w, v.w, s2))));
    }
    s1 += __shfl_xor(s1, 1, 64); s2 += __shfl_xor(s2, 1, 64);
    s1 += __shfl_xor(s1, 2, 64); s2 += __shfl_xor(s2, 2, 64);
    if (p == 0) {
      float mean = s1 * (1.f / 512.f);
      float var = s2 * (1.f / 512.f) - mean * mean;
      meanS[r] = mean;
      rstdS[r] = rsqrtf(var + 1e-5f);
    }
  }
  floatx4 acc[2][2] = {};
  const float* Ap = A + (size_t)(bm * 64 + sr) * 512 + sk;
  const u16* Bp = Bw + (size_t)(bn * 64 + sr) * 512 + sk;
  float4 a0 = *(const float4*)(Ap);
  float4 a1 = *(const float4*)(Ap + 4);
  float4 a2 = *(const float4*)(Ap + 8);
  float4 a3 = *(const float4*)(Ap + 12);
  uint4 b0 = *(const uint4*)(Bp);
  uint4 b1 = *(const uint4*)(Bp + 8);
  __syncthreads();  // stats + gs/bs visible
  const float mu = meanS[sr], rs = rstdS[sr];
  for (int k0 = 0; k0 < 512; k0 += 64) {
    if (k0) __syncthreads();
    {
      int c0 = k0 + sk;
      float t[16] = {a0.x, a0.y, a0.z, a0.w, a1.x, a1.y, a1.z, a1.w,
                     a2.x, a2.y, a2.z, a2.w, a3.x, a3.y, a3.z, a3.w};
      unsigned pw[8];
#pragma unroll
      for (int e = 0; e < 8; e++) {
        float lo = (t[2 * e] - mu) * rs * gs[c0 + 2 * e] + bs[c0 + 2 * e];
        float hi = (t[2 * e + 1] - mu) * rs * gs[c0 + 2 * e + 1] + bs[c0 + 2 * e + 1];
        pw[e] = pk2(lo, hi);
      }
      *(uint4*)&As[sr][sk] = make_uint4(pw[0], pw[1], pw[2], pw[3]);
      *(uint4*)&As[sr][sk + 8] = make_uint4(pw[4], pw[5], pw[6], pw[7]);
      *(uint4*)&Bs[sr][sk] = b0;
      *(uint4*)&Bs[sr][sk + 8] = b1;
    }
    __syncthreads();
    if (k0 + 64 < 512) {
      a0 = *(const float4*)(Ap + k0 + 64);
      a1 = *(const float4*)(Ap + k0 + 68);
      a2 = *(const float4*)(Ap + k0 + 72);
      a3 = *(const float4*)(Ap + k0 + 76);
      b0 = *(const uint4*)(Bp + k0 + 64);
      b1 = *(const uint4*)(Bp + k0 + 72);
    }
#pragma unroll
    for (int kk = 0; kk < 2; kk++) {
      short8 af0 = *(const short8*)&As[wm * 32 + l16][kk * 32 + quad * 8];
      short8 af1 = *(const short8*)&As[wm * 32 + 16 + l16][kk * 32 + quad * 8];
      short8 bf0 = *(const short8*)&Bs[wn * 32 + l16][kk * 32 + quad * 8];
      short8 bf1 = *(const short8*)&Bs[wn * 32 + 16 + l16][kk * 32 + quad * 8];
      acc[0][0] = __builtin_amdgcn_mfma_f32_16x16x32_bf16(af0, bf0, acc[0][0], 0, 0, 0);
      acc[0][1] = __builtin_amdgcn_mfma_f32_16x16x32_bf16(af0, bf1, acc[0][1], 0, 0, 0);
      acc[1][0] = __builtin_amdgcn_mfma_f32_16x16x32_bf16(af1, bf0, acc[1][0], 0, 0, 0);
      acc[1][1] = __builtin_amdgcn_mfma_f32_16x16x32_bf16(af1, bf1, acc[1][1], 0, 0, 0);
    }
  }
#pragma unroll
  for (int mt = 0; mt < 2; mt++)
#pragma unroll
    for (int r = 0; r < 4; r++) {
      int row = bm * 64 + wm * 32 + mt * 16 + quad * 4 + r;
#pragma unroll
      for (int nt = 0; nt < 2; nt++) {
        int col = bn * 64 + wn * 32 + nt * 16 + l16;
        float v = acc[mt][nt][r];
        float xv = X[(size_t)row * 512 + col];
        C[(size_t)row * 512 + col] = xv + v / (1.f + __expf(-v));
      }
    }
}

// ---------- fused prep_attn: RoPE q,k -> bf16 (b,h,t,32) | V -> bf16 (b,h,64,T) ----------
__global__ __launch_bounds__(256) void prep_attn(const float* __restrict__ qkv, const float* __restrict__ qgain,
                                                 u16* __restrict__ qr, u16* __restrict__ kr,
                                                 u16* __restrict__ Vt) {
  const int bi = blockIdx.x, tid = threadIdx.x;
  if (bi < 2048) {  // RoPE
    int gid = bi * 256 + tid;
    int o = gid & 15;
    int t = (gid >> 4) & 2047;
    int h = (gid >> 15) & 7;
    int b = gid >> 18;
    const float* row = qkv + (size_t)(b * 2048 + t) * 1024;
    float freq = powf(10000.f, -(float)o / 16.f);
    float ang = (float)t * freq;
    float s, c;
    sincosf(ang, &s, &c);
    float g = qgain[h] * 0.17677669529663687f;  // gain * 1/sqrt(32)
    int qb = h * 32;
    float q0 = row[qb + o], q1 = row[qb + o + 16];
    float k0 = row[256 + qb + o], k1 = row[256 + qb + o + 16];
    u16* qo = qr + ((size_t)((b * 8 + h) * 2048 + t)) * 32;
    u16* ko = kr + ((size_t)((b * 8 + h) * 2048 + t)) * 32;
    qo[o] = f2b((q0 * c - q1 * s) * g);
    qo[o + 16] = f2b((q1 * c + q0 * s) * g);
    ko[o] = f2b(k0 * c - k1 * s);
    ko[o + 16] = f2b(k1 * c + k0 * s);
  } else {  // V transpose
    int idx = bi - 2048;
    const int tt = idx & 31, bh = idx >> 5;
    const int b = bh >> 3, h = bh & 7;
    __shared__ u16 Ts[64][72];
    const int r = tid >> 2, q = tid & 3;
    const float* src = qkv + ((size_t)(b * 2048 + tt * 64 + r)) * 1024 + 512 + h * 64 + q * 16;
#pragma unroll
    for (int j = 0; j < 4; j++) {
      float4 v = *(const float4*)(src + j * 4);
      Ts[q * 16 + j * 4 + 0][r] = f2b(v.x);
      Ts[q * 16 + j * 4 + 1][r] = f2b(v.y);
      Ts[q * 16 + j * 4 + 2][r] = f2b(v.z);
      Ts[q * 16 + j * 4 + 3][r] = f2b(v.w);
    }
    __syncthreads();
    u16* dst = Vt + ((size_t)(bh * 64 + r)) * 2048 + tt * 64 + q * 16;
    *(uint4*)dst = *(const uint4*)&Ts[r][q * 16];
    *(uint4*)(dst + 8) = *(const uint4*)&Ts[r][q * 16 + 8];
  }
}

// ---------- MFMA causal attention, split-K S=4, no-max softmax, K/V prefetch ----------
__global__ __launch_bounds__(256) void attn_split(const u16* __restrict__ Qb, const u16* __restrict__ Kb,
                                                  const u16* __restrict__ Vt, float* __restrict__ PO,
                                                  float* __restrict__ PL) {
  const int bi = blockIdx.x;               // 2048 blocks
  const int bh = bi & 15;
  const int q0i = (bi >> 4) & 15;
  const int rem = bi >> 8;                 // 0..7; blocks j+256k share a CU:
  const int qt = (rem & 1) ? (31 - q0i) : q0i;  // per-CU work = const 33 iters
  const int s = rem >> 1;                  // split index 0..3
  const int tid = threadIdx.x;
  const int w = tid >> 6, lane = tid & 63, quad = lane >> 4, l16 = lane & 15;
  __shared__ u16 Vts[64][72];
  __shared__ u16 Ps[4][16][72];

  const int kt_beg = ((qt + 1) * s) >> 2;
  const int kt_end = ((qt + 1) * (s + 1)) >> 2;

  short8 qfrag = *(const short8*)(Qb + ((size_t)(bh * 2048 + qt * 64 + w * 16 + l16)) * 32 + quad * 8);
  floatx4 o_acc[4] = {};
  float l_part[4] = {0.f, 0.f, 0.f, 0.f};
  const u16* Kbase = Kb + (size_t)bh * 2048 * 32;
  const u16* Vtb = Vt + (size_t)bh * 64 * 2048;
  const int vr = tid >> 2, vc = (tid & 3) << 4;

  uint4 v0 = {}, v1 = {};
  short8 kf[4] = {};
  if (kt_beg < kt_end) {
    const u16* src = Vtb + (size_t)vr * 2048 + kt_beg * 64 + vc;
    v0 = *(const uint4*)src;
    v1 = *(const uint4*)(src + 8);
#pragma unroll
    for (int nt = 0; nt < 4; nt++)
      kf[nt] = *(const short8*)(Kbase + (size_t)(kt_beg * 64 + nt * 16 + l16) * 32 + quad * 8);
  }

  for (int kt = kt_beg; kt < kt_end; ++kt) {
    __syncthreads();
    *(uint4*)&Vts[vr][vc] = v0;
    *(uint4*)&Vts[vr][vc + 8] = v1;
    __syncthreads();
    const bool more = (kt + 1 < kt_end);
    uint4 v0n = {}, v1n = {};
    short8 kfn[4] = {};
    if (more) {
      const u16* src = Vtb + (size_t)vr * 2048 + (kt + 1) * 64 + vc;
      v0n = *(const uint4*)src;
      v1n = *(const uint4*)(src + 8);
#pragma unroll
      for (int nt = 0; nt < 4; nt++)
        kfn[nt] = *(const short8*)(Kbase + (size_t)((kt + 1) * 64 + nt * 16 + l16) * 32 + quad * 8);
    }

    floatx4 s_acc[4];
#pragma unroll
    for (int nt = 0; nt < 4; nt++) {
      floatx4 zz = {0.f, 0.f, 0.f, 0.f};
      s_acc[nt] = __builtin_amdgcn_mfma_f32_16x16x32_bf16(qfrag, kf[nt], zz, 0, 0, 0);
    }
    const bool diag = (kt == qt);
#pragma unroll
    for (int r = 0; r < 4; r++) {
      int mloc = w * 16 + quad * 4 + r;
      float psum = 0.f;
#pragma unroll
      for (int nt = 0; nt < 4; nt++) {
        float p = __expf(s_acc[nt][r]);  // scores O(1): no max subtraction needed
        if (diag && (nt * 16 + l16) > mloc) p = 0.f;
        psum += p;
        Ps[w][quad * 4 + r][nt * 16 + l16] = f2b(p);
      }
      l_part[r] += psum;
    }
#pragma unroll
    for (int kc = 0; kc < 2; kc++) {
      short8 pf = *(const short8*)&Ps[w][l16][kc * 32 + quad * 8];
#pragma unroll
      for (int nt = 0; nt < 4; nt++) {
        short8 vf = *(const short8*)&Vts[nt * 16 + l16][kc * 32 + quad * 8];
        o_acc[nt] = __builtin_amdgcn_mfma_f32_16x16x32_bf16(pf, vf, o_acc[nt], 0, 0, 0);
      }
    }
    v0 = v0n; v1 = v1n;
#pragma unroll
    for (int nt = 0; nt < 4; nt++) kf[nt] = kfn[nt];
  }

  // store partials (zero for empty ranges — combine sums all 4)
  const int pidx = (bh * 32 + qt) * 4 + s;
  float* pob = PO + (size_t)pidx * 4096;
#pragma unroll
  for (int r = 0; r < 4; r++) {
    float ls = l_part[r];
#pragma unroll
    for (int mk = 1; mk < 16; mk <<= 1) ls += __shfl_xor(ls, mk, 64);
    int row = w * 16 + quad * 4 + r;
#pragma unroll
    for (int nt = 0; nt < 4; nt++) pob[row * 64 + nt * 16 + l16] = o_acc[nt][r];
    if (l16 == 0) PL[pidx * 64 + row] = ls;
  }
}

// ---------- combine 4 split-K partials + self-align + permute to (b,t,512) bf16 ----------
// grid must be 8192: 32768 (bh,tok) rows, 4 per block.
__global__ __launch_bounds__(256) void attn_combine(const float* __restrict__ PO, const float* __restrict__ PL,
                                                    const float* __restrict__ qkv, u16* __restrict__ y2b) {
  int ridx = blockIdx.x * 4 + (threadIdx.x >> 6);  // 0..32767
  int lane = threadIdx.x & 63;
  int bh = ridx >> 11, tok = ridx & 2047;
  int qt = tok >> 6, row = tok & 63;
  int pidx = (bh * 32 + qt) * 4;
  const float* p0 = PO + (size_t)pidx * 4096 + row * 64 + lane;
  float o = p0[0] + p0[4096] + p0[8192] + p0[12288];
  const float* pl = PL + pidx * 64 + row;
  float l = pl[0] + pl[64] + pl[128] + pl[192];
  float yv = o / l;
  int b = bh >> 3, h = bh & 7;
  float vv = qkv[(size_t)(b * 2048 + tok) * 1024 + 512 + h * 64 + lane];
  float ss = vv * vv, dot = yv * vv;
#pragma unroll
  for (int mk = 1; mk < 64; mk <<= 1) {
    ss += __shfl_xor(ss, mk, 64);
    dot += __shfl_xor(dot, mk, 64);
  }
  float coef = dot / fmaxf(ss, 1e-24f);
  y2b[(size_t)(b * 2048 + tok) * 512 + h * 64 + lane] = f2b(yv - coef * vv);
}

// ---------- fused RMS + 512->32 projection + softplus temp + tanh ----------
__global__ __launch_bounds__(256) void final_rms(const float* __restrict__ he2, const float* __restrict__ wout,
                                                 const float* __restrict__ ct, float* __restrict__ z) {
  int tok = blockIdx.x * 8 + (threadIdx.x >> 5);
  int n = threadIdx.x & 31;
  const float* rr = he2 + (size_t)tok * 512;
  float ss = 0.f;
#pragma unroll
  for (int j = 0; j < 4; j++) {
    float4 v = ((const float4*)rr)[j * 32 + n];
    ss = fmaf(v.x, v.x, fmaf(v.y, v.y, fmaf(v.z, v.z, fmaf(v.w, v.w, ss))));
  }
#pragma unroll
  for (int mk = 1; mk < 32; mk <<= 1) ss += __shfl_xor(ss, mk, 64);
  float rinv = rsqrtf(ss * (1.f / 512.f) + 1e-6f);
  const float* w = wout + (size_t)n * 512;
  float acc = 0.f;
  for (int d = 0; d < 512; d += 4) {
    float4 rv = *(const float4*)(rr + d);
    float4 wv = *(const float4*)(w + d);
    acc = fmaf(rv.x, wv.x, acc);
    acc = fmaf(rv.y, wv.y, acc);
    acc = fmaf(rv.z, wv.z, acc);
    acc = fmaf(rv.w, wv.w, acc);
  }
  float c = ct[n];
  float sp = (c > 20.f) ? c : log1pf(__expf(c));
  z[(size_t)tok * 32 + n] = tanhf(acc * rinv / (sp + 1e-4f));
}

extern "C" void kernel_launch(void* const* d_in, const int* in_sizes, int n_in,
                              void* d_out, int out_size, void* d_ws, size_t ws_size,
                              hipStream_t stream) {
  const float* x = (const float*)d_in[0];
  const float* qp = (const float*)d_in[1];
  const float* kp = (const float*)d_in[2];
  const float* wv = (const float*)d_in[3];
  const float* wpr = (const float*)d_in[4];
  const float* qg = (const float*)d_in[5];
  const float* w0 = (const float*)d_in[6];
  const float* g1 = (const float*)d_in[7];
  const float* b1 = (const float*)d_in[8];
  const float* w1 = (const float*)d_in[9];
  const float* g2 = (const float*)d_in[10];
  const float* b2 = (const float*)d_in[11];
  const float* w2 = (const float*)d_in[12];
  const float* wout = (const float*)d_in[13];
  const float* ct = (const float*)d_in[14];
  float* z = (float*)d_out;

  float* ws = (float*)d_ws;
  const size_t MEG = 1024 * 1024;
  float* A_QKV = ws;                          // [0..4M) fp32 qkv; later he0 fp32
  u16* A_Qb = (u16*)(ws + 4 * MEG);           // [4M..4.5M)
  u16* A_Kb = (u16*)(ws + 4 * MEG + 524288);  // [4.5M..5M)
  u16* A_Vt = (u16*)(ws + 5 * MEG);           // [5M..6M)
  float* A_HE2 = ws + 4 * MEG;                // alias (after attention)
  float* A_Y = ws + 6 * MEG;                  // [6M..8M): he1 fp32
  float* A_H = ws + 8 * MEG;                  // [8M..10M): h fp32
  u16* A_Y2b = (u16*)(ws + 10 * MEG);         // [10M..11M)
  u16* A_Hb = (u16*)(ws + 11 * MEG);          // [11M..12M)
  u16* XB = (u16*)(ws + 13 * MEG);            // [13M..14M)
  u16* WCATb = (u16*)(ws + 14 * MEG);         // [14M..14.25M)
  u16* WPRb = WCATb + 524288;
  u16* W0b = WPRb + 262144;
  u16* W1b = W0b + 262144;
  u16* W2b = W1b + 262144;
  float* A_PO = ws + 16 * MEG;                // [16M..24M): 4 partials x 16x32 x 4096
  float* A_PL = ws + 24 * MEG;                // 131072 floats

  hipLaunchKernelGGL(prep_cast, dim3(5120), dim3(256), 0, stream, x, wpr, w0, w1, w2, qp, kp, wv,
                     XB, WPRb, W0b, W1b, W2b, WCATb);
  hipLaunchKernelGGL((mgemm<0, false>), dim3(16, 64), dim3(256), 0, stream, XB, WCATb,
                     (const float*)nullptr, A_QKV, (u16*)nullptr, 1024);
  hipLaunchKernelGGL(prep_attn, dim3(2560), dim3(256), 0, stream, A_QKV, qg, A_Qb, A_Kb, A_Vt);
  hipLaunchKernelGGL(attn_split, dim3(2048), dim3(256), 0, stream, A_Qb, A_Kb, A_Vt, A_PO, A_PL);
  hipLaunchKernelGGL(attn_combine, dim3(8192), dim3(256), 0, stream, A_PO, A_PL, A_QKV, A_Y2b);
  // h = y2 @ wpr^T + x   (dual store fp32+bf16)
  hipLaunchKernelGGL((mgemm<1, true>), dim3(8, 64), dim3(256), 0, stream, A_Y2b, WPRb, x, A_H, A_Hb, 512);
  // he0 = h @ w0^T  (fp32 only; LN fused into next GEMM)
  hipLaunchKernelGGL((mgemm<0, false>), dim3(8, 64), dim3(256), 0, stream, A_Hb, W0b,
                     (const float*)nullptr, A_QKV, (u16*)nullptr, 512);
  // he1 = h + silu(LN(he0) @ w1^T)
  hipLaunchKernelGGL(mgemm_ln, dim3(8, 64), dim3(256), 0, stream, A_QKV, W1b, g1, b1, A_H, A_Y);
  // he2 = he1 + silu(LN(he1) @ w2^T)
  hipLaunchKernelGGL(mgemm_ln, dim3(8, 64), dim3(256), 0, stream, A_Y, W2b, g2, b2, A_Y, A_HE2);
  hipLaunchKernelGGL(final_rms, dim3(512), dim3(256), 0, stream, A_HE2, wout, ct, z);
}

// Round 10
// 224.897 us; speedup vs baseline: 1.0779x; 1.0779x over previous
//
#include <hip/hip_runtime.h>
#include <math.h>

typedef unsigned short u16;
typedef __attribute__((ext_vector_type(8))) short short8;
typedef __attribute__((ext_vector_type(4))) float floatx4;

__device__ __forceinline__ float b2f(u16 u) { return __uint_as_float(((unsigned)u) << 16); }
__device__ __forceinline__ u16 f2b(float f) {
  unsigned u = __float_as_uint(f);
  return (u16)((u + 0x7fffu + ((u >> 16) & 1u)) >> 16);
}

// ---------- fused prep: cast x -> bf16 | cast 4 weights | build Wcat ----------
__global__ __launch_bounds__(256) void prep_cast(const float* __restrict__ x, const float* __restrict__ wpr,
                                                 const float* __restrict__ w0, const float* __restrict__ w1,
                                                 const float* __restrict__ w2, const float* __restrict__ qp,
                                                 const float* __restrict__ kp, const float* __restrict__ wv,
                                                 u16* __restrict__ XB, u16* __restrict__ WPRb,
                                                 u16* __restrict__ W0b, u16* __restrict__ W1b,
                                                 u16* __restrict__ W2b, u16* __restrict__ wcat) {
  int bi = blockIdx.x, tid = threadIdx.x;
  if (bi < 2048) {                       // cast_x: 524288 float4s
    int i = bi * 256 + tid;
    float4 v = ((const float4*)x)[i];
    ushort4 o; o.x = f2b(v.x); o.y = f2b(v.y); o.z = f2b(v.z); o.w = f2b(v.w);
    ((ushort4*)XB)[i] = o;
  } else if (bi < 3072) {                // cast 4x 512x512 weights: 262144 float4s
    int i = (bi - 2048) * 256 + tid;
    int sel = i >> 16, j = i & 65535;
    const float* s = sel == 0 ? wpr : sel == 1 ? w0 : sel == 2 ? w1 : w2;
    u16* d = sel == 0 ? WPRb : sel == 1 ? W0b : sel == 2 ? W1b : W2b;
    float4 v = ((const float4*)s)[j];
    ushort4 o; o.x = f2b(v.x); o.y = f2b(v.y); o.z = f2b(v.z); o.w = f2b(v.w);
    ((ushort4*)d)[j] = o;
  } else {                               // build_wcat: 524288 elements
    int i = (bi - 3072) * 256 + tid;
    int d = i & 511, c = i >> 9;
    float v;
    if (c < 512) {
      int hh = c >> 5, o = c & 31;
      const float* src = (hh < 8) ? qp : kp;
      int h = hh & 7;
      v = src[(h * 512 + d) * 32 + o];
    } else {
      v = wv[(c - 512) * 512 + d];
    }
    wcat[i] = f2b(v);
  }
}

// ---------- bf16 MFMA GEMM (64x64 tile): used for the QKV projection (N=1024) ----------
template <int EPI, bool DUAL>
__global__ __launch_bounds__(256) void mgemm(const u16* __restrict__ A, const u16* __restrict__ Bw,
                                             const float* __restrict__ X, float* __restrict__ C,
                                             u16* __restrict__ Cb, int N) {
  __shared__ u16 As[64][72];
  __shared__ u16 Bs[64][72];
  const int tid = threadIdx.x;
  const int bm = blockIdx.y, bn = blockIdx.x;
  const int lane = tid & 63, wave = tid >> 6;
  const int wm = wave >> 1, wn = wave & 1;
  const int quad = lane >> 4, l16 = lane & 15;
  const int sr = tid >> 2;
  const int sk = (tid & 3) << 4;
  floatx4 acc[2][2] = {};
  const u16* Ap = A + (size_t)(bm * 64 + sr) * 512 + sk;
  const u16* Bp = Bw + (size_t)(bn * 64 + sr) * 512 + sk;
  uint4 a0 = *(const uint4*)(Ap);
  uint4 a1 = *(const uint4*)(Ap + 8);
  uint4 b0 = *(const uint4*)(Bp);
  uint4 b1 = *(const uint4*)(Bp + 8);
  for (int k0 = 0; k0 < 512; k0 += 64) {
    __syncthreads();
    *(uint4*)&As[sr][sk] = a0;
    *(uint4*)&As[sr][sk + 8] = a1;
    *(uint4*)&Bs[sr][sk] = b0;
    *(uint4*)&Bs[sr][sk + 8] = b1;
    __syncthreads();
    if (k0 + 64 < 512) {
      a0 = *(const uint4*)(Ap + k0 + 64);
      a1 = *(const uint4*)(Ap + k0 + 72);
      b0 = *(const uint4*)(Bp + k0 + 64);
      b1 = *(const uint4*)(Bp + k0 + 72);
    }
#pragma unroll
    for (int kk = 0; kk < 2; kk++) {
      short8 af0 = *(const short8*)&As[wm * 32 + l16][kk * 32 + quad * 8];
      short8 af1 = *(const short8*)&As[wm * 32 + 16 + l16][kk * 32 + quad * 8];
      short8 bf0 = *(const short8*)&Bs[wn * 32 + l16][kk * 32 + quad * 8];
      short8 bf1 = *(const short8*)&Bs[wn * 32 + 16 + l16][kk * 32 + quad * 8];
      acc[0][0] = __builtin_amdgcn_mfma_f32_16x16x32_bf16(af0, bf0, acc[0][0], 0, 0, 0);
      acc[0][1] = __builtin_amdgcn_mfma_f32_16x16x32_bf16(af0, bf1, acc[0][1], 0, 0, 0);
      acc[1][0] = __builtin_amdgcn_mfma_f32_16x16x32_bf16(af1, bf0, acc[1][0], 0, 0, 0);
      acc[1][1] = __builtin_amdgcn_mfma_f32_16x16x32_bf16(af1, bf1, acc[1][1], 0, 0, 0);
    }
  }
#pragma unroll
  for (int mt = 0; mt < 2; mt++)
#pragma unroll
    for (int r = 0; r < 4; r++) {
      int row = bm * 64 + wm * 32 + mt * 16 + quad * 4 + r;
#pragma unroll
      for (int nt = 0; nt < 2; nt++) {
        int col = bn * 64 + wn * 32 + nt * 16 + l16;
        float v = acc[mt][nt][r];
        if (EPI == 1) v += X[(size_t)row * 512 + col];
        C[(size_t)row * N + col] = v;
        if (DUAL) Cb[(size_t)row * N + col] = f2b(v);
      }
    }
}

// ---------- bf16 MFMA GEMM (32x64 tile, 1024 blocks -> 4/CU): the N=512 chain GEMMs ----------
// C[Mx512] = A[Mx512] @ B^T (+ epilogue). EPI: 0 plain, 1 +X, 2 X + silu(acc). DUAL: bf16 copy.
template <int EPI, bool DUAL>
__global__ __launch_bounds__(256) void mgemm32(const u16* __restrict__ A, const u16* __restrict__ Bw,
                                               const float* __restrict__ X, float* __restrict__ C,
                                               u16* __restrict__ Cb) {
  __shared__ u16 As[32][72];
  __shared__ u16 Bs[64][72];
  const int tid = threadIdx.x;
  const int bm = blockIdx.y, bn = blockIdx.x;
  const int lane = tid & 63, wave = tid >> 6;
  const int wm = wave >> 1, wn = wave & 1;       // wave rows 16, cols 32
  const int quad = lane >> 4, l16 = lane & 15;
  const int ar = tid >> 3, ak = (tid & 7) << 3;  // A staging: 32 rows x 64 u16, 1 uint4/thread
  const int br = tid >> 2, bk = (tid & 3) << 4;  // B staging: 64 rows x 64 u16, 2 uint4/thread
  floatx4 acc[2] = {};
  const u16* Ap = A + (size_t)(bm * 32 + ar) * 512 + ak;
  const u16* Bp = Bw + (size_t)(bn * 64 + br) * 512 + bk;
  uint4 a0 = *(const uint4*)(Ap);
  uint4 b0 = *(const uint4*)(Bp);
  uint4 b1 = *(const uint4*)(Bp + 8);
  for (int k0 = 0; k0 < 512; k0 += 64) {
    __syncthreads();
    *(uint4*)&As[ar][ak] = a0;
    *(uint4*)&Bs[br][bk] = b0;
    *(uint4*)&Bs[br][bk + 8] = b1;
    __syncthreads();
    if (k0 + 64 < 512) {  // prefetch next tile
      a0 = *(const uint4*)(Ap + k0 + 64);
      b0 = *(const uint4*)(Bp + k0 + 64);
      b1 = *(const uint4*)(Bp + k0 + 72);
    }
#pragma unroll
    for (int kk = 0; kk < 2; kk++) {
      short8 af = *(const short8*)&As[wm * 16 + l16][kk * 32 + quad * 8];
      short8 bf0 = *(const short8*)&Bs[wn * 32 + l16][kk * 32 + quad * 8];
      short8 bf1 = *(const short8*)&Bs[wn * 32 + 16 + l16][kk * 32 + quad * 8];
      acc[0] = __builtin_amdgcn_mfma_f32_16x16x32_bf16(af, bf0, acc[0], 0, 0, 0);
      acc[1] = __builtin_amdgcn_mfma_f32_16x16x32_bf16(af, bf1, acc[1], 0, 0, 0);
    }
  }
#pragma unroll
  for (int r = 0; r < 4; r++) {
    int row = bm * 32 + wm * 16 + quad * 4 + r;
#pragma unroll
    for (int nt = 0; nt < 2; nt++) {
      int col = bn * 64 + wn * 32 + nt * 16 + l16;
      float v = acc[nt][r];
      if (EPI == 1) {
        v += X[(size_t)row * 512 + col];
      } else if (EPI == 2) {
        float xv = X[(size_t)row * 512 + col];
        v = xv + v / (1.f + __expf(-v));
      }
      C[(size_t)row * 512 + col] = v;
      if (DUAL) Cb[(size_t)row * 512 + col] = f2b(v);
    }
  }
}

// ---------- fused prep_attn: RoPE q,k -> bf16 (b,h,t,32) | V -> bf16 (b,h,64,T) ----------
__global__ __launch_bounds__(256) void prep_attn(const float* __restrict__ qkv, const float* __restrict__ qgain,
                                                 u16* __restrict__ qr, u16* __restrict__ kr,
                                                 u16* __restrict__ Vt) {
  const int bi = blockIdx.x, tid = threadIdx.x;
  if (bi < 2048) {  // RoPE
    int gid = bi * 256 + tid;
    int o = gid & 15;
    int t = (gid >> 4) & 2047;
    int h = (gid >> 15) & 7;
    int b = gid >> 18;
    const float* row = qkv + (size_t)(b * 2048 + t) * 1024;
    float freq = powf(10000.f, -(float)o / 16.f);
    float ang = (float)t * freq;
    float s, c;
    sincosf(ang, &s, &c);
    float g = qgain[h] * 0.17677669529663687f;  // gain * 1/sqrt(32)
    int qb = h * 32;
    float q0 = row[qb + o], q1 = row[qb + o + 16];
    float k0 = row[256 + qb + o], k1 = row[256 + qb + o + 16];
    u16* qo = qr + ((size_t)((b * 8 + h) * 2048 + t)) * 32;
    u16* ko = kr + ((size_t)((b * 8 + h) * 2048 + t)) * 32;
    qo[o] = f2b((q0 * c - q1 * s) * g);
    qo[o + 16] = f2b((q1 * c + q0 * s) * g);
    ko[o] = f2b(k0 * c - k1 * s);
    ko[o + 16] = f2b(k1 * c + k0 * s);
  } else {  // V transpose
    int idx = bi - 2048;
    const int tt = idx & 31, bh = idx >> 5;
    const int b = bh >> 3, h = bh & 7;
    __shared__ u16 Ts[64][72];
    const int r = tid >> 2, q = tid & 3;
    const float* src = qkv + ((size_t)(b * 2048 + tt * 64 + r)) * 1024 + 512 + h * 64 + q * 16;
#pragma unroll
    for (int j = 0; j < 4; j++) {
      float4 v = *(const float4*)(src + j * 4);
      Ts[q * 16 + j * 4 + 0][r] = f2b(v.x);
      Ts[q * 16 + j * 4 + 1][r] = f2b(v.y);
      Ts[q * 16 + j * 4 + 2][r] = f2b(v.z);
      Ts[q * 16 + j * 4 + 3][r] = f2b(v.w);
    }
    __syncthreads();
    u16* dst = Vt + ((size_t)(bh * 64 + r)) * 2048 + tt * 64 + q * 16;
    *(uint4*)dst = *(const uint4*)&Ts[r][q * 16];
    *(uint4*)(dst + 8) = *(const uint4*)&Ts[r][q * 16 + 8];
  }
}

// ---------- MFMA causal attention, split-K (S=2), no-max softmax, K/V prefetch ----------
__global__ __launch_bounds__(256) void attn_split(const u16* __restrict__ Qb, const u16* __restrict__ Kb,
                                                  const u16* __restrict__ Vt, float* __restrict__ PO,
                                                  float* __restrict__ PL) {
  const int bi = blockIdx.x;               // 1024 blocks
  const int bh = bi & 15;
  const int q0i = (bi >> 4) & 15;
  const int rem = bi >> 8;                 // blocks j,j+256,j+512,j+768 share a CU:
  const int qt = (rem & 1) ? (31 - q0i) : q0i;  // per-CU work = const 33 iters
  const int s = rem >> 1;
  const int tid = threadIdx.x;
  const int w = tid >> 6, lane = tid & 63, quad = lane >> 4, l16 = lane & 15;
  __shared__ u16 Vts[64][72];
  __shared__ u16 Ps[4][16][72];

  const int mid = (qt + 1) >> 1;
  const int kt_beg = s ? mid : 0;
  const int kt_end = s ? (qt + 1) : mid;

  short8 qfrag = *(const short8*)(Qb + ((size_t)(bh * 2048 + qt * 64 + w * 16 + l16)) * 32 + quad * 8);
  floatx4 o_acc[4] = {};
  float l_part[4] = {0.f, 0.f, 0.f, 0.f};
  const u16* Kbase = Kb + (size_t)bh * 2048 * 32;
  const u16* Vtb = Vt + (size_t)bh * 64 * 2048;
  const int vr = tid >> 2, vc = (tid & 3) << 4;

  uint4 v0 = {}, v1 = {};
  short8 kf[4] = {};
  if (kt_beg < kt_end) {
    const u16* src = Vtb + (size_t)vr * 2048 + kt_beg * 64 + vc;
    v0 = *(const uint4*)src;
    v1 = *(const uint4*)(src + 8);
#pragma unroll
    for (int nt = 0; nt < 4; nt++)
      kf[nt] = *(const short8*)(Kbase + (size_t)(kt_beg * 64 + nt * 16 + l16) * 32 + quad * 8);
  }

  for (int kt = kt_beg; kt < kt_end; ++kt) {
    __syncthreads();
    *(uint4*)&Vts[vr][vc] = v0;
    *(uint4*)&Vts[vr][vc + 8] = v1;
    __syncthreads();
    const bool more = (kt + 1 < kt_end);
    uint4 v0n = {}, v1n = {};
    short8 kfn[4] = {};
    if (more) {  // prefetch next K/V; latency overlaps exp+MFMA below
      const u16* src = Vtb + (size_t)vr * 2048 + (kt + 1) * 64 + vc;
      v0n = *(const uint4*)src;
      v1n = *(const uint4*)(src + 8);
#pragma unroll
      for (int nt = 0; nt < 4; nt++)
        kfn[nt] = *(const short8*)(Kbase + (size_t)((kt + 1) * 64 + nt * 16 + l16) * 32 + quad * 8);
    }

    floatx4 s_acc[4];
#pragma unroll
    for (int nt = 0; nt < 4; nt++) {
      floatx4 zz = {0.f, 0.f, 0.f, 0.f};
      s_acc[nt] = __builtin_amdgcn_mfma_f32_16x16x32_bf16(qfrag, kf[nt], zz, 0, 0, 0);
    }
    const bool diag = (kt == qt);
#pragma unroll
    for (int r = 0; r < 4; r++) {
      int mloc = w * 16 + quad * 4 + r;
      float psum = 0.f;
#pragma unroll
      for (int nt = 0; nt < 4; nt++) {
        float p = __expf(s_acc[nt][r]);  // scores O(1): no max subtraction needed
        if (diag && (nt * 16 + l16) > mloc) p = 0.f;
        psum += p;
        Ps[w][quad * 4 + r][nt * 16 + l16] = f2b(p);
      }
      l_part[r] += psum;
    }
#pragma unroll
    for (int kc = 0; kc < 2; kc++) {
      short8 pf = *(const short8*)&Ps[w][l16][kc * 32 + quad * 8];
#pragma unroll
      for (int nt = 0; nt < 4; nt++) {
        short8 vf = *(const short8*)&Vts[nt * 16 + l16][kc * 32 + quad * 8];
        o_acc[nt] = __builtin_amdgcn_mfma_f32_16x16x32_bf16(pf, vf, o_acc[nt], 0, 0, 0);
      }
    }
    v0 = v0n; v1 = v1n;
#pragma unroll
    for (int nt = 0; nt < 4; nt++) kf[nt] = kfn[nt];
  }

  // store partials (unnormalized O, per-row l)
  const int pidx = (bh * 32 + qt) * 2 + s;
  float* pob = PO + (size_t)pidx * 4096;
#pragma unroll
  for (int r = 0; r < 4; r++) {
    float ls = l_part[r];
#pragma unroll
    for (int mk = 1; mk < 16; mk <<= 1) ls += __shfl_xor(ls, mk, 64);
    int row = w * 16 + quad * 4 + r;
#pragma unroll
    for (int nt = 0; nt < 4; nt++) pob[row * 64 + nt * 16 + l16] = o_acc[nt][r];
    if (l16 == 0) PL[pidx * 64 + row] = ls;
  }
}

// ---------- combine split-K partials + self-align + permute to (b,t,512) bf16 ----------
// grid must be 8192: 32768 (bh,tok) rows, 4 per block.
__global__ __launch_bounds__(256) void attn_combine(const float* __restrict__ PO, const float* __restrict__ PL,
                                                    const float* __restrict__ qkv, u16* __restrict__ y2b) {
  int ridx = blockIdx.x * 4 + (threadIdx.x >> 6);  // 0..32767
  int lane = threadIdx.x & 63;
  int bh = ridx >> 11, tok = ridx & 2047;
  int qt = tok >> 6, row = tok & 63;
  int pidx = (bh * 32 + qt) * 2;
  const float* p0 = PO + (size_t)pidx * 4096 + row * 64;
  float o = p0[lane] + p0[4096 + lane];
  float l = PL[pidx * 64 + row] + PL[(pidx + 1) * 64 + row];
  float yv = o / l;
  int b = bh >> 3, h = bh & 7;
  float vv = qkv[(size_t)(b * 2048 + tok) * 1024 + 512 + h * 64 + lane];
  float ss = vv * vv, dot = yv * vv;
#pragma unroll
  for (int mk = 1; mk < 64; mk <<= 1) {
    ss += __shfl_xor(ss, mk, 64);
    dot += __shfl_xor(dot, mk, 64);
  }
  float coef = dot / fmaxf(ss, 1e-24f);
  y2b[(size_t)(b * 2048 + tok) * 512 + h * 64 + lane] = f2b(yv - coef * vv);
}

// ---------- LayerNorm (bf16 out): one wave per 512-row ----------
__global__ __launch_bounds__(256) void ln_kernel(const float* __restrict__ in, const float* __restrict__ g,
                                                 const float* __restrict__ bglob, u16* __restrict__ outb) {
  int row = blockIdx.x * 4 + (threadIdx.x >> 6);
  int lane = threadIdx.x & 63;
  const float* rp = in + (size_t)row * 512 + lane * 8;
  float4 a = *(const float4*)rp;
  float4 b = *(const float4*)(rp + 4);
  float v[8] = {a.x, a.y, a.z, a.w, b.x, b.y, b.z, b.w};
  float s = 0.f;
#pragma unroll
  for (int e = 0; e < 8; e++) s += v[e];
#pragma unroll
  for (int mk = 1; mk < 64; mk <<= 1) s += __shfl_xor(s, mk, 64);
  float mean = s * (1.f / 512.f);
  float vs = 0.f;
#pragma unroll
  for (int e = 0; e < 8; e++) { float d = v[e] - mean; vs = fmaf(d, d, vs); }
#pragma unroll
  for (int mk = 1; mk < 64; mk <<= 1) vs += __shfl_xor(vs, mk, 64);
  float inv = rsqrtf(vs * (1.f / 512.f) + 1e-5f);
  int c0 = lane * 8;
  u16* op = outb + (size_t)row * 512 + c0;
  ushort4 o1, o2;
  o1.x = f2b((v[0] - mean) * inv * g[c0 + 0] + bglob[c0 + 0]);
  o1.y = f2b((v[1] - mean) * inv * g[c0 + 1] + bglob[c0 + 1]);
  o1.z = f2b((v[2] - mean) * inv * g[c0 + 2] + bglob[c0 + 2]);
  o1.w = f2b((v[3] - mean) * inv * g[c0 + 3] + bglob[c0 + 3]);
  o2.x = f2b((v[4] - mean) * inv * g[c0 + 4] + bglob[c0 + 4]);
  o2.y = f2b((v[5] - mean) * inv * g[c0 + 5] + bglob[c0 + 5]);
  o2.z = f2b((v[6] - mean) * inv * g[c0 + 6] + bglob[c0 + 6]);
  o2.w = f2b((v[7] - mean) * inv * g[c0 + 7] + bglob[c0 + 7]);
  *(ushort4*)op = o1;
  *(ushort4*)(op + 4) = o2;
}

// ---------- fused RMS + 512->32 projection + softplus temp + tanh ----------
__global__ __launch_bounds__(256) void final_rms(const float* __restrict__ he2, const float* __restrict__ wout,
                                                 const float* __restrict__ ct, float* __restrict__ z) {
  int tok = blockIdx.x * 8 + (threadIdx.x >> 5);
  int n = threadIdx.x & 31;
  const float* rr = he2 + (size_t)tok * 512;
  float ss = 0.f;
#pragma unroll
  for (int j = 0; j < 4; j++) {
    float4 v = ((const float4*)rr)[j * 32 + n];
    ss = fmaf(v.x, v.x, fmaf(v.y, v.y, fmaf(v.z, v.z, fmaf(v.w, v.w, ss))));
  }
#pragma unroll
  for (int mk = 1; mk < 32; mk <<= 1) ss += __shfl_xor(ss, mk, 64);
  float rinv = rsqrtf(ss * (1.f / 512.f) + 1e-6f);
  const float* w = wout + (size_t)n * 512;
  float acc = 0.f;
  for (int d = 0; d < 512; d += 4) {
    float4 rv = *(const float4*)(rr + d);
    float4 wv = *(const float4*)(w + d);
    acc = fmaf(rv.x, wv.x, acc);
    acc = fmaf(rv.y, wv.y, acc);
    acc = fmaf(rv.z, wv.z, acc);
    acc = fmaf(rv.w, wv.w, acc);
  }
  float c = ct[n];
  float sp = (c > 20.f) ? c : log1pf(__expf(c));
  z[(size_t)tok * 32 + n] = tanhf(acc * rinv / (sp + 1e-4f));
}

extern "C" void kernel_launch(void* const* d_in, const int* in_sizes, int n_in,
                              void* d_out, int out_size, void* d_ws, size_t ws_size,
                              hipStream_t stream) {
  const float* x = (const float*)d_in[0];
  const float* qp = (const float*)d_in[1];
  const float* kp = (const float*)d_in[2];
  const float* wv = (const float*)d_in[3];
  const float* wpr = (const float*)d_in[4];
  const float* qg = (const float*)d_in[5];
  const float* w0 = (const float*)d_in[6];
  const float* g1 = (const float*)d_in[7];
  const float* b1 = (const float*)d_in[8];
  const float* w1 = (const float*)d_in[9];
  const float* g2 = (const float*)d_in[10];
  const float* b2 = (const float*)d_in[11];
  const float* w2 = (const float*)d_in[12];
  const float* wout = (const float*)d_in[13];
  const float* ct = (const float*)d_in[14];
  float* z = (float*)d_out;

  float* ws = (float*)d_ws;
  const size_t MEG = 1024 * 1024;
  float* A_QKV = ws;                          // [0..4M) fp32 qkv; later he0
  u16* A_Qb = (u16*)(ws + 4 * MEG);           // [4M..4.5M)
  u16* A_Kb = (u16*)(ws + 4 * MEG + 524288);  // [4.5M..5M)
  u16* A_Vt = (u16*)(ws + 5 * MEG);           // [5M..6M)
  float* A_HE2 = ws + 4 * MEG;                // alias (after attention)
  float* A_PO = ws + 6 * MEG;                 // [6M..10M): split-K partial O (4M floats)
  float* A_Y = ws + 6 * MEG;                  // later: he1 fp32 [6M..8M)
  float* A_H = ws + 8 * MEG;                  // later: h fp32 [8M..10M)
  u16* A_Y2b = (u16*)(ws + 10 * MEG);         // [10M..11M)
  u16* A_Hb = (u16*)(ws + 11 * MEG);          // [11M..12M)
  u16* XB = (u16*)(ws + 13 * MEG);            // [13M..14M); reused as PL after QKV gemm
  float* A_PL = ws + 13 * MEG;                // 64K floats (aliases dead XB)
  u16* WCATb = (u16*)(ws + 14 * MEG);         // [14M..14.25M)
  u16* WPRb = WCATb + 524288;
  u16* W0b = WPRb + 262144;
  u16* W1b = W0b + 262144;
  u16* W2b = W1b + 262144;

  hipLaunchKernelGGL(prep_cast, dim3(5120), dim3(256), 0, stream, x, wpr, w0, w1, w2, qp, kp, wv,
                     XB, WPRb, W0b, W1b, W2b, WCATb);
  hipLaunchKernelGGL((mgemm<0, false>), dim3(16, 64), dim3(256), 0, stream, XB, WCATb,
                     (const float*)nullptr, A_QKV, (u16*)nullptr, 1024);
  hipLaunchKernelGGL(prep_attn, dim3(2560), dim3(256), 0, stream, A_QKV, qg, A_Qb, A_Kb, A_Vt);
  hipLaunchKernelGGL(attn_split, dim3(1024), dim3(256), 0, stream, A_Qb, A_Kb, A_Vt, A_PO, A_PL);
  hipLaunchKernelGGL(attn_combine, dim3(8192), dim3(256), 0, stream, A_PO, A_PL, A_QKV, A_Y2b);
  // h = y2 @ wpr^T + x   (dual store fp32+bf16)
  hipLaunchKernelGGL((mgemm32<1, true>), dim3(8, 128), dim3(256), 0, stream, A_Y2b, WPRb, x, A_H, A_Hb);
  // he0 = h @ w0^T
  hipLaunchKernelGGL((mgemm32<0, false>), dim3(8, 128), dim3(256), 0, stream, A_Hb, W0b,
                     (const float*)nullptr, A_QKV, (u16*)nullptr);
  hipLaunchKernelGGL(ln_kernel, dim3(1024), dim3(256), 0, stream, A_QKV, g1, b1, (u16*)(ws + 12 * MEG));
  // he1 = h + silu(ln1 @ w1^T)
  hipLaunchKernelGGL((mgemm32<2, false>), dim3(8, 128), dim3(256), 0, stream, (u16*)(ws + 12 * MEG),
                     W1b, A_H, A_Y, (u16*)nullptr);
  hipLaunchKernelGGL(ln_kernel, dim3(1024), dim3(256), 0, stream, A_Y, g2, b2, (u16*)(ws + 12 * MEG));
  // he2 = he1 + silu(ln2 @ w2^T)
  hipLaunchKernelGGL((mgemm32<2, false>), dim3(8, 128), dim3(256), 0, stream, (u16*)(ws + 12 * MEG),
                     W2b, A_Y, A_HE2, (u16*)nullptr);
  hipLaunchKernelGGL(final_rms, dim3(512), dim3(256), 0, stream, A_HE2, wout, ct, z);
}